// Round 16
// baseline (36.526 us; speedup 1.0000x reference)
//
#include <hip/hip_runtime.h>

namespace {

constexpr int Nn = 256;
constexpr int Bn = 64;
constexpr int SEG = 8;
constexpr int NSEG = Nn / SEG;   // 32

// Gaussian taps, sigma = 5*0.15+0.35 = 1.1
constexpr float KW0 = 0.07076638f;
constexpr float KW1 = 0.24446039f;
constexpr float KW2 = 0.36954646f;

constexpr float DEF_OFF   = 1.00784313725490196f;   // 1 + 2/255
constexpr float SCALE     = 0.01568627450980392f;   // 4/255
constexpr float INV_SCALE = 63.75f;                 // 255/4
constexpr float TWO255    = 0.00784313725490196f;   // 2/255 = seq step
constexpr float PW        = 0.0078125f;             // 2/256

__device__ __forceinline__ int reflN(int i) {
    if (i < 0) i = -i;
    if (i >= Nn) i = 2 * (Nn - 1) - i;
    return i;
}

__device__ __forceinline__ float seqf(int t) {
    return (float)(2 * t - (Nn - 1)) * (1.0f / (float)(Nn - 1));
}

// Bijective XCD swizzle: 2048 blocks, 8 XCDs, 256-block chunks
// -> all 32 segs of a batch (8 whole batches) share one XCD's L2.
__device__ __forceinline__ void segb(int lin, int& seg, int& b) {
    int wg = (lin & 7) * 256 + (lin >> 3);
    b = wg >> 5;
    seg = wg & (NSEG - 1);
}

// ---- kP: ch1 conv -> per-segment column partial sums (2MB) -----------------
__global__ __launch_bounds__(256, 8) void kP_kernel(const float* __restrict__ prim,
                                                    float* __restrict__ partial) {
    const int j = threadIdx.x;
    int seg, b;
    segb(blockIdx.x, seg, b);
    const int i0 = seg * SEG;
    const float* c1 = prim + ((size_t)b * 2 + 1) * Nn * Nn;

    float a[SEG + 5];
    #pragma unroll
    for (int t = 0; t < SEG + 5; ++t) a[t] = c1[reflN(i0 - 3 + t) * Nn + j];

    __shared__ float vb[(SEG + 1) * Nn];
    #pragma unroll
    for (int r = 0; r < SEG + 1; ++r)   // v-conv centers i0-1 .. i0+7
        vb[r * Nn + j] = KW0 * (a[r] + a[r + 4]) + KW1 * (a[r + 1] + a[r + 3]) + KW2 * a[r + 2];
    __syncthreads();

    const int jm2 = reflN(j - 2), jm1 = reflN(j - 1), jp1 = reflN(j + 1), jp2 = reflN(j + 2);
    auto hc = [&](const float* v) {
        return KW0 * (v[jm2] + v[jp2]) + KW1 * (v[jm1] + v[jp1]) + KW2 * v[j];
    };

    float hprev = hc(&vb[0]);
    float psum = 0.0f;
    #pragma unroll
    for (int r = 0; r < SEG; ++r) {
        float h = hc(&vb[(r + 1) * Nn]);
        float hm = (r == 0 && seg == 0) ? 0.0f : hprev;
        psum += fmaxf((h - hm + TWO255) * INV_SCALE, 0.0f);
        hprev = h;
    }
    partial[((size_t)b * NSEG + seg) * Nn + j] = psum;
}

// ---- kF: fused dual-channel conv + scans + cumsum + pipelined bilinear -----
// 4 barriers (was 6): both channels' vconv share one 17-row buffer, all 25
// column loads issue in one MLP window. convb doubles as the c1 image buffer.
// LDS 27.8KB -> 5 blocks/CU. (256,4): do NOT squeeze the allocator
// (R8/R9/R11: tighter bounds or bigger arrays => ~100MB scratch spill).
__global__ __launch_bounds__(256, 4) void kF_kernel(const float* __restrict__ prim,
                                                    const float* __restrict__ image,
                                                    const float* __restrict__ partial,
                                                    float* __restrict__ outp) {
    const int j = threadIdx.x;
    int seg, b;
    segb(blockIdx.x, seg, b);
    const int i0 = seg * SEG;
    const int lane = j & 63;
    const int wave = j >> 6;

    __shared__ float imgA[SEG + 2][Nn];        // 10 rows: image c0, later c2
    __shared__ float convb[2 * SEG + 1][Nn];   // 17 rows: vconv both ch; later image c1
    __shared__ float wsum[SEG][4];

    // async image-channel prefetch: 10 rows, one 16B DMA per lane per row
    auto issue_prefetch = [&](int c, float (*buf)[Nn]) {
        for (int r = wave; r < SEG + 2; r += 4) {
            int row = min(max(i0 - 1 + r, 0), Nn - 1);
            const float* src = image + ((size_t)(b * 3 + c) * Nn + row) * Nn + lane * 4;
#if defined(__has_builtin) && __has_builtin(__builtin_amdgcn_global_load_lds)
            __builtin_amdgcn_global_load_lds(
                (const __attribute__((address_space(1))) void*)(const void*)src,
                (__attribute__((address_space(3))) void*)(void*)&buf[r][0],
                16, 0, 0);
#else
            ((float4*)&buf[r][0])[lane] = ((const float4*)(src - lane * 4))[lane];
#endif
        }
    };

    // ---- 1) c0 image DMA + ALL column loads (both channels) + carry: one
    //         big MLP window, everything overlaps ----
    issue_prefetch(0, imgA);

    const float* c0 = prim + (size_t)b * 2 * Nn * Nn;
    const float* c1 = c0 + (size_t)Nn * Nn;

    float a1[SEG + 5], a0[SEG + 4];
    #pragma unroll
    for (int t = 0; t < SEG + 5; ++t) a1[t] = c1[reflN(i0 - 3 + t) * Nn + j];
    #pragma unroll
    for (int t = 0; t < SEG + 4; ++t) a0[t] = c0[reflN(i0 - 2 + t) * Nn + j];

    const float* pb = partial + (size_t)b * NSEG * Nn + j;
    float carry = 0.0f;
    #pragma unroll
    for (int k = 0; k < NSEG - 1; ++k) {
        float p = pb[(size_t)k * Nn];
        carry += (k < seg) ? p : 0.0f;
    }

    // ---- 2) vconv both channels into convb: ch1 rows 0..8, ch0 rows 9..16 --
    #pragma unroll
    for (int r = 0; r < SEG + 1; ++r)
        convb[r][j] = KW0 * (a1[r] + a1[r + 4]) + KW1 * (a1[r + 1] + a1[r + 3]) + KW2 * a1[r + 2];
    #pragma unroll
    for (int r = 0; r < SEG; ++r)
        convb[SEG + 1 + r][j] = KW0 * (a0[r] + a0[r + 4]) + KW1 * (a0[r + 1] + a0[r + 3]) + KW2 * a0[r + 2];
    __syncthreads();                            // B1

    const int jm3 = reflN(j - 3), jm2 = reflN(j - 2), jm1 = reflN(j - 1),
              jp1 = reflN(j + 1), jp2 = reflN(j + 2);
    auto hc = [&](const float* v) {
        return KW0 * (v[jm2] + v[jp2]) + KW1 * (v[jm1] + v[jp1]) + KW2 * v[j];
    };

    // ---- 3a) ch1 hconv -> column diffs (register-local along i) ----
    float acc_iy[SEG];   // accu now; overwritten by iy in step 5
    {
        float hprev = hc(&convb[0][0]);
        #pragma unroll
        for (int r = 0; r < SEG; ++r) {
            float h = hc(&convb[r + 1][0]);
            float hm = (r == 0 && seg == 0) ? 0.0f : hprev;
            acc_iy[r] = fmaxf((h - hm + TWO255) * INV_SCALE, 0.0f);
            hprev = h;
        }
    }

    // ---- 3b) ch0 hconv (h + hm; 6 consecutive reads merge to ds_read2) ->
    //          row diffs -> 256-wide scans ----
    float ix[SEG];
    {
        #pragma unroll
        for (int r = 0; r < SEG; ++r) {
            const float* v = &convb[SEG + 1 + r][0];
            float h  = hc(v);
            float hm = KW0 * (v[jm3] + v[jp1]) + KW1 * (v[jm2] + v[j]) + KW2 * v[jm1];
            if (j == 0) hm = 0.0f;
            float s = fmaxf((h - hm + TWO255) * INV_SCALE, 0.0f);
            #pragma unroll
            for (int off = 1; off < 64; off <<= 1) {
                float u = __shfl_up(s, off, 64);
                if (lane >= off) s += u;
            }
            ix[r] = s;
            if (lane == 63) wsum[r][wave] = s;
        }
    }
    __syncthreads();   // B2: all convb reads done, wsum visible, c0 DMA drained

    // ---- 4) c1 image DMA into convb (now free); scan fixup -> x-coords ----
    issue_prefetch(1, convb);
    {
        const float sq_j = seqf(j);
        #pragma unroll
        for (int r = 0; r < SEG; ++r) {
            float add = 0.0f;
            for (int w = 0; w < wave; ++w) add += wsum[r][w];
            float samp = (ix[r] + add) * SCALE - DEF_OFF;
            float p = fminf(fmaxf(samp - sq_j, -PW), PW);
            float g = fminf(fmaxf(p + sq_j, -1.0f), 1.0f);
            ix[r] = (g + 1.0f) * 127.5f;
        }
    }

    // ---- 5) column cumsum with carry -> y-coords (in place) ----
    {
        float cum = carry;
        #pragma unroll
        for (int k = 0; k < SEG; ++k) {
            cum += acc_iy[k];
            float samp = cum * SCALE - DEF_OFF;
            float sq = seqf(i0 + k);
            float p  = fminf(fmaxf(samp - sq, -PW), PW);
            float gy = fminf(fmaxf(p + sq, -1.0f), 1.0f);
            acc_iy[k] = (gy + 1.0f) * 127.5f;
        }
    }

    // ---- 6) interp. samp clipped to [-1,1] => ix,iy in [0,255] EXACTLY, so
    // boundary weights are naturally zero — no validity logic. Unconditional
    // neighbor reads pair into ds_read2_b32; weight-0 overreads land in
    // adjacent initialized (finite) LDS. ly0 <= 8 always.
    auto interp_store = [&](int c, const float (*tile)[Nn]) {
        #pragma unroll
        for (int k = 0; k < SEG; ++k) {
            float fx = floorf(ix[k]), fy = floorf(acc_iy[k]);
            float wx1 = ix[k] - fx, wy1 = acc_iy[k] - fy;
            int x0 = (int)fx;
            int ly0 = (int)fy - i0 + 1;
            const float* p0 = &tile[ly0][x0];
            float v00 = p0[0],  v10 = p0[1];
            float v01 = p0[Nn], v11 = p0[Nn + 1];
            float top = v00 + wx1 * (v10 - v00);
            float bot = v01 + wx1 * (v11 - v01);
            float v = top + wy1 * (bot - top);
            __builtin_nontemporal_store(v, &outp[(((size_t)b * 3 + c) * Nn + (i0 + k)) * Nn + j]);
        }
    };

    interp_store(0, imgA);
    __syncthreads();              // B3: drains c1 DMA, imgA reads done
    issue_prefetch(2, imgA);
    interp_store(1, (const float (*)[Nn])convb);
    __syncthreads();              // B4: drains c2 DMA, convb reads done
    interp_store(2, imgA);
}

}  // namespace

extern "C" void kernel_launch(void* const* d_in, const int* in_sizes, int n_in,
                              void* d_out, int out_size, void* d_ws, size_t ws_size,
                              hipStream_t stream) {
    const float* image = (const float*)d_in[0];   // (B,3,N,N) f32
    const float* prim  = (const float*)d_in[1];   // (B,2,N,N) f32
    float* outp = (float*)d_out;                  // (B,3,N,N) f32
    float* partial = (float*)d_ws;                // B*NSEG*N floats (2MB)

    kP_kernel<<<NSEG * Bn, 256, 0, stream>>>(prim, partial);
    kF_kernel<<<NSEG * Bn, 256, 0, stream>>>(prim, image, partial, outp);
}

// Round 17
// 34.358 us; speedup vs baseline: 1.0631x; 1.0631x over previous
//
#include <hip/hip_runtime.h>

namespace {

constexpr int Nn = 256;
constexpr int Bn = 64;
constexpr int SEG = 8;
constexpr int NSEG = Nn / SEG;   // 32

// Gaussian taps, sigma = 5*0.15+0.35 = 1.1
constexpr float KW0 = 0.07076638f;
constexpr float KW1 = 0.24446039f;
constexpr float KW2 = 0.36954646f;

constexpr float DEF_OFF   = 1.00784313725490196f;   // 1 + 2/255
constexpr float SCALE     = 0.01568627450980392f;   // 4/255
constexpr float INV_SCALE = 63.75f;                 // 255/4
constexpr float TWO255    = 0.00784313725490196f;   // 2/255 = seq step
constexpr float PW        = 0.0078125f;             // 2/256

__device__ __forceinline__ int reflN(int i) {
    if (i < 0) i = -i;
    if (i >= Nn) i = 2 * (Nn - 1) - i;
    return i;
}

__device__ __forceinline__ float seqf(int t) {
    return (float)(2 * t - (Nn - 1)) * (1.0f / (float)(Nn - 1));
}

// wave64 inclusive scan, pure VALU (DPP): row_shr 1/2/4/8, then
// row_bcast:15 (rows 1,3) and row_bcast:31 (rows 2,3). bound_ctrl=1 + old=0
// make invalid/masked lanes contribute 0.
__device__ __forceinline__ float wave_iscan(float x) {
    float s = x;
    int t;
    t = __builtin_amdgcn_update_dpp(0, __float_as_int(s), 0x111, 0xF, 0xF, true);
    s += __int_as_float(t);
    t = __builtin_amdgcn_update_dpp(0, __float_as_int(s), 0x112, 0xF, 0xF, true);
    s += __int_as_float(t);
    t = __builtin_amdgcn_update_dpp(0, __float_as_int(s), 0x114, 0xF, 0xF, true);
    s += __int_as_float(t);
    t = __builtin_amdgcn_update_dpp(0, __float_as_int(s), 0x118, 0xF, 0xF, true);
    s += __int_as_float(t);
    t = __builtin_amdgcn_update_dpp(0, __float_as_int(s), 0x142, 0xA, 0xF, true);
    s += __int_as_float(t);
    t = __builtin_amdgcn_update_dpp(0, __float_as_int(s), 0x143, 0xC, 0xF, true);
    s += __int_as_float(t);
    return s;
}

// Bijective XCD swizzle: 2048 blocks, 8 XCDs, 256-block chunks
// -> all 32 segs of a batch (8 whole batches) share one XCD's L2.
__device__ __forceinline__ void segb(int lin, int& seg, int& b) {
    int wg = (lin & 7) * 256 + (lin >> 3);
    b = wg >> 5;
    seg = wg & (NSEG - 1);
}

// ---- kP: ch1 conv -> per-segment column partial sums (2MB) -----------------
__global__ __launch_bounds__(256, 8) void kP_kernel(const float* __restrict__ prim,
                                                    float* __restrict__ partial) {
    const int j = threadIdx.x;
    int seg, b;
    segb(blockIdx.x, seg, b);
    const int i0 = seg * SEG;
    const float* c1 = prim + ((size_t)b * 2 + 1) * Nn * Nn;

    float a[SEG + 5];
    #pragma unroll
    for (int t = 0; t < SEG + 5; ++t) a[t] = c1[reflN(i0 - 3 + t) * Nn + j];

    __shared__ float vb[(SEG + 1) * Nn];
    #pragma unroll
    for (int r = 0; r < SEG + 1; ++r)   // v-conv centers i0-1 .. i0+7
        vb[r * Nn + j] = KW0 * (a[r] + a[r + 4]) + KW1 * (a[r + 1] + a[r + 3]) + KW2 * a[r + 2];
    __syncthreads();

    const int jm2 = reflN(j - 2), jm1 = reflN(j - 1), jp1 = reflN(j + 1), jp2 = reflN(j + 2);
    auto hc = [&](const float* v) {
        return KW0 * (v[jm2] + v[jp2]) + KW1 * (v[jm1] + v[jp1]) + KW2 * v[j];
    };

    float hprev = hc(&vb[0]);
    float psum = 0.0f;
    #pragma unroll
    for (int r = 0; r < SEG; ++r) {
        float h = hc(&vb[(r + 1) * Nn]);
        float hm = (r == 0 && seg == 0) ? 0.0f : hprev;
        psum += fmaxf((h - hm + TWO255) * INV_SCALE, 0.0f);
        hprev = h;
    }
    partial[((size_t)b * NSEG + seg) * Nn + j] = psum;
}

// ---- kF: fused dual-channel conv + DPP scans + cumsum + pipelined bilinear -
// 4 barriers; both channels' vconv share one 17-row buffer; scan on the VALU
// (DPP) instead of the LDS pipe (was 48 ds_bpermute/thread).
// LDS 27.8KB -> 5 blocks/CU. (256,4): do NOT squeeze the allocator
// (R8/R9/R11: tighter bounds or bigger arrays => ~100MB scratch spill).
__global__ __launch_bounds__(256, 4) void kF_kernel(const float* __restrict__ prim,
                                                    const float* __restrict__ image,
                                                    const float* __restrict__ partial,
                                                    float* __restrict__ outp) {
    const int j = threadIdx.x;
    int seg, b;
    segb(blockIdx.x, seg, b);
    const int i0 = seg * SEG;
    const int lane = j & 63;
    const int wave = j >> 6;

    __shared__ float imgA[SEG + 2][Nn];        // 10 rows: image c0, later c2
    __shared__ float convb[2 * SEG + 1][Nn];   // 17 rows: vconv both ch; later image c1
    __shared__ float wsum[SEG][4];

    // async image-channel prefetch: 10 rows, one 16B DMA per lane per row
    auto issue_prefetch = [&](int c, float (*buf)[Nn]) {
        for (int r = wave; r < SEG + 2; r += 4) {
            int row = min(max(i0 - 1 + r, 0), Nn - 1);
            const float* src = image + ((size_t)(b * 3 + c) * Nn + row) * Nn + lane * 4;
#if defined(__has_builtin) && __has_builtin(__builtin_amdgcn_global_load_lds)
            __builtin_amdgcn_global_load_lds(
                (const __attribute__((address_space(1))) void*)(const void*)src,
                (__attribute__((address_space(3))) void*)(void*)&buf[r][0],
                16, 0, 0);
#else
            ((float4*)&buf[r][0])[lane] = ((const float4*)(src - lane * 4))[lane];
#endif
        }
    };

    // ---- 1) c0 image DMA + ALL column loads (both channels) + carry: one
    //         big MLP window, everything overlaps ----
    issue_prefetch(0, imgA);

    const float* c0 = prim + (size_t)b * 2 * Nn * Nn;
    const float* c1 = c0 + (size_t)Nn * Nn;

    float a1[SEG + 5], a0[SEG + 4];
    #pragma unroll
    for (int t = 0; t < SEG + 5; ++t) a1[t] = c1[reflN(i0 - 3 + t) * Nn + j];
    #pragma unroll
    for (int t = 0; t < SEG + 4; ++t) a0[t] = c0[reflN(i0 - 2 + t) * Nn + j];

    const float* pb = partial + (size_t)b * NSEG * Nn + j;
    float carry = 0.0f;
    #pragma unroll
    for (int k = 0; k < NSEG - 1; ++k) {
        float p = pb[(size_t)k * Nn];
        carry += (k < seg) ? p : 0.0f;
    }

    // ---- 2) vconv both channels into convb: ch1 rows 0..8, ch0 rows 9..16 --
    #pragma unroll
    for (int r = 0; r < SEG + 1; ++r)
        convb[r][j] = KW0 * (a1[r] + a1[r + 4]) + KW1 * (a1[r + 1] + a1[r + 3]) + KW2 * a1[r + 2];
    #pragma unroll
    for (int r = 0; r < SEG; ++r)
        convb[SEG + 1 + r][j] = KW0 * (a0[r] + a0[r + 4]) + KW1 * (a0[r + 1] + a0[r + 3]) + KW2 * a0[r + 2];
    __syncthreads();                            // B1

    const int jm3 = reflN(j - 3), jm2 = reflN(j - 2), jm1 = reflN(j - 1),
              jp1 = reflN(j + 1), jp2 = reflN(j + 2);
    auto hc = [&](const float* v) {
        return KW0 * (v[jm2] + v[jp2]) + KW1 * (v[jm1] + v[jp1]) + KW2 * v[j];
    };

    // ---- 3a) ch1 hconv -> column diffs (register-local along i) ----
    float acc_iy[SEG];   // accu now; overwritten by iy in step 5
    {
        float hprev = hc(&convb[0][0]);
        #pragma unroll
        for (int r = 0; r < SEG; ++r) {
            float h = hc(&convb[r + 1][0]);
            float hm = (r == 0 && seg == 0) ? 0.0f : hprev;
            acc_iy[r] = fmaxf((h - hm + TWO255) * INV_SCALE, 0.0f);
            hprev = h;
        }
    }

    // ---- 3b) ch0 hconv (h + hm; consecutive reads merge to ds_read2) ->
    //          row diffs -> DPP wave scans (VALU, no LDS pipe) ----
    float ix[SEG];
    {
        #pragma unroll
        for (int r = 0; r < SEG; ++r) {
            const float* v = &convb[SEG + 1 + r][0];
            float h  = hc(v);
            float hm = KW0 * (v[jm3] + v[jp1]) + KW1 * (v[jm2] + v[j]) + KW2 * v[jm1];
            if (j == 0) hm = 0.0f;
            float s = wave_iscan(fmaxf((h - hm + TWO255) * INV_SCALE, 0.0f));
            ix[r] = s;
            if (lane == 63) wsum[r][wave] = s;
        }
    }
    __syncthreads();   // B2: all convb reads done, wsum visible, c0 DMA drained

    // ---- 4) c1 image DMA into convb (now free); scan fixup -> x-coords ----
    issue_prefetch(1, convb);
    {
        const float sq_j = seqf(j);
        #pragma unroll
        for (int r = 0; r < SEG; ++r) {
            float add = 0.0f;
            for (int w = 0; w < wave; ++w) add += wsum[r][w];
            float samp = (ix[r] + add) * SCALE - DEF_OFF;
            float p = fminf(fmaxf(samp - sq_j, -PW), PW);
            float g = fminf(fmaxf(p + sq_j, -1.0f), 1.0f);
            ix[r] = (g + 1.0f) * 127.5f;
        }
    }

    // ---- 5) column cumsum with carry -> y-coords (in place) ----
    {
        float cum = carry;
        #pragma unroll
        for (int k = 0; k < SEG; ++k) {
            cum += acc_iy[k];
            float samp = cum * SCALE - DEF_OFF;
            float sq = seqf(i0 + k);
            float p  = fminf(fmaxf(samp - sq, -PW), PW);
            float gy = fminf(fmaxf(p + sq, -1.0f), 1.0f);
            acc_iy[k] = (gy + 1.0f) * 127.5f;
        }
    }

    // ---- 6) interp. samp clipped to [-1,1] => ix,iy in [0,255] EXACTLY, so
    // boundary weights are naturally zero — no validity logic. Unconditional
    // neighbor reads pair into ds_read2_b32; weight-0 overreads land in
    // adjacent initialized (finite) LDS. ly0 <= 8 always.
    auto interp_store = [&](int c, const float (*tile)[Nn]) {
        #pragma unroll
        for (int k = 0; k < SEG; ++k) {
            float fx = floorf(ix[k]), fy = floorf(acc_iy[k]);
            float wx1 = ix[k] - fx, wy1 = acc_iy[k] - fy;
            int x0 = (int)fx;
            int ly0 = (int)fy - i0 + 1;
            const float* p0 = &tile[ly0][x0];
            float v00 = p0[0],  v10 = p0[1];
            float v01 = p0[Nn], v11 = p0[Nn + 1];
            float top = v00 + wx1 * (v10 - v00);
            float bot = v01 + wx1 * (v11 - v01);
            float v = top + wy1 * (bot - top);
            __builtin_nontemporal_store(v, &outp[(((size_t)b * 3 + c) * Nn + (i0 + k)) * Nn + j]);
        }
    };

    interp_store(0, imgA);
    __syncthreads();              // B3: drains c1 DMA, imgA reads done
    issue_prefetch(2, imgA);
    interp_store(1, (const float (*)[Nn])convb);
    __syncthreads();              // B4: drains c2 DMA, convb reads done
    interp_store(2, imgA);
}

}  // namespace

extern "C" void kernel_launch(void* const* d_in, const int* in_sizes, int n_in,
                              void* d_out, int out_size, void* d_ws, size_t ws_size,
                              hipStream_t stream) {
    const float* image = (const float*)d_in[0];   // (B,3,N,N) f32
    const float* prim  = (const float*)d_in[1];   // (B,2,N,N) f32
    float* outp = (float*)d_out;                  // (B,3,N,N) f32
    float* partial = (float*)d_ws;                // B*NSEG*N floats (2MB)

    kP_kernel<<<NSEG * Bn, 256, 0, stream>>>(prim, partial);
    kF_kernel<<<NSEG * Bn, 256, 0, stream>>>(prim, image, partial, outp);
}